// Round 7
// baseline (353.933 us; speedup 1.0000x reference)
//
#include <hip/hip_runtime.h>
#include <math.h>

#define HDIM 512
#define BATCH 128

typedef _Float16 f16x8 __attribute__((ext_vector_type(8)));
typedef float f32x4 __attribute__((ext_vector_type(4)));

__device__ __forceinline__ float fast_tanh(float x) {
  float e = __expf(2.0f * x);
  return 1.0f - 2.0f / (e + 1.0f);
}

__device__ __forceinline__ void gload_lds16(const void* g, void* l) {
  __builtin_amdgcn_global_load_lds(
      (const __attribute__((address_space(1))) unsigned int*)g,
      (__attribute__((address_space(3))) unsigned int*)l, 16, 0, 0);
}

// ---------------------------------------------------------------------------
// W [512 k][512 n] fp32 -> W2 [16 kt][512 n][32 k] f16, 64B rows swizzled
// byte ^= (n&3)<<4 (involution; matches the GEMM's ds_read swizzle, G21).
// grid (128, 3).
// ---------------------------------------------------------------------------
__global__ __launch_bounds__(256) void cvt_w3_kernel(
    const float* __restrict__ Wt, const float* __restrict__ Wa,
    const float* __restrict__ Wd, _Float16* __restrict__ W2t,
    _Float16* __restrict__ W2a, _Float16* __restrict__ W2d) {
  const int i = blockIdx.x * 256 + threadIdx.x;  // 512 n * 64 chunk-slots
  if (i >= 512 * 64) return;
  const float* W = (blockIdx.y == 0) ? Wt : (blockIdx.y == 1) ? Wa : Wd;
  _Float16* W2 = (blockIdx.y == 0) ? W2t : (blockIdx.y == 1) ? W2a : W2d;
  const int n = i & 511, g = i >> 9;   // g = global 8-k chunk 0..63
  const int kt = g >> 2, kc = g & 3;   // kt 0..15, kc 0..3 (8 k each)
  f16x8 h;
#pragma unroll
  for (int j = 0; j < 8; ++j)
    h[j] = (_Float16)W[(size_t)(kt * 32 + kc * 8 + j) * HDIM + n];
  char* dst = (char*)W2 + (size_t)kt * 32768 + n * 64 + ((kc * 16) ^ ((n & 3) << 4));
  *(f16x8*)dst = h;
}

// ---------------------------------------------------------------------------
// Merged fused logit GEMM over 4 segments (tok / node / desc-anchor / desc-neg):
//   logits[m] = sum_n v[n] * tanh( (A@W)[m,n] + bias[n] )   (+c skipped)
// A fp32 [M][512] read ONCE (BN = 512 = full N), reg-staged -> f16 swizzled
// ds_write (tanh fused for node). B from pre-swizzled W2 via global_load_lds.
// BM=128, BK=32, 512 thr = 8 waves, wave tile 128x64, acc 8x4. LDS 80 KB dbuf.
// Pipeline: issue A-regs(t+1)+B-lds(t+1) BEFORE MFMA(t); cvt+ds_write after;
// __syncthreads end-of-iter (drain covered by MFMA phase). Full-N block =>
// cross-wave LDS reduce + direct logits store (no atomics, no pre-zero).
// ---------------------------------------------------------------------------
__global__ __launch_bounds__(512, 1) void gemm_logits_merged_kernel(
    const float* __restrict__ A_tok, const float* __restrict__ A_node,
    const float* __restrict__ A_da, const float* __restrict__ A_dn,
    const _Float16* __restrict__ W2t, const _Float16* __restrict__ W2a,
    const _Float16* __restrict__ W2d,
    const float* __restrict__ bt, const float* __restrict__ vt,
    const float* __restrict__ ba, const float* __restrict__ va,
    const float* __restrict__ bd, const float* __restrict__ vd,
    float* __restrict__ logits_tok, float* __restrict__ logits_node,
    float* __restrict__ logits_desc) {
  __shared__ __align__(16) _Float16 As[2][128 * 32];  // 2 x 8 KB
  __shared__ __align__(16) _Float16 Bs[2][512 * 32];  // 2 x 32 KB

  const int tid = threadIdx.x;
  const int raw = (int)blockIdx.x;               // 1280 blocks
  const int swz = (raw & 7) * 160 + (raw >> 3);  // XCD-bijective (1280%8==0)

  // segment decode: [0,512) tok, [512,1024) node, [1024,1152) da, [1152,1280) dn
  int id, mb;
  if (swz < 512)       { id = 0; mb = swz; }
  else if (swz < 1024) { id = 1; mb = swz - 512; }
  else if (swz < 1152) { id = 2; mb = swz - 1024; }
  else                 { id = 3; mb = swz - 1152; }
  const float* A = (id == 0) ? A_tok : (id == 1) ? A_node : (id == 2) ? A_da : A_dn;
  const _Float16* W2 = (id == 0) ? W2t : (id == 1) ? W2a : W2d;
  const float* bias = (id == 0) ? bt : (id == 1) ? ba : bd;
  const float* vvec = (id == 0) ? vt : (id == 1) ? va : vd;
  float* logits = (id == 0) ? logits_tok
                : (id == 1) ? logits_node
                : (id == 2) ? logits_desc : (logits_desc + 16384);
  const bool do_tanh = (id == 1);
  const size_t m0 = (size_t)mb * 128;

  const int lane = tid & 63, wid = tid >> 6;
  const int tx = lane & 15, qd = lane >> 4;

  // A staging coords: 128 rows x 32 floats; 4 thr/row, 8 floats (2 float4) each
  const int arow = tid >> 2;        // 0..127
  const int apart = tid & 3;        // 0..3 -> float cols apart*8..+8
  const float* arowp = A + (m0 + arow) * HDIM + apart * 8;
  const int awbyte = arow * 64 + ((apart * 16) ^ ((arow & 3) << 4));

  f32x4 acc[8][4];
#pragma unroll
  for (int i = 0; i < 8; ++i)
#pragma unroll
    for (int j = 0; j < 4; ++j) acc[i][j] = (f32x4){0.f, 0.f, 0.f, 0.f};

  float4 ar0, ar1;
  auto LOAD_A = [&](int t) {
    const float* p = arowp + t * 32;
    ar0 = ((const float4*)p)[0];
    ar1 = ((const float4*)p)[1];
  };
  auto STAGE_B = [&](int buf, int t) {
    const char* b = (const char*)W2 + (size_t)t * 32768;
#pragma unroll
    for (int p = 0; p < 4; ++p)
      gload_lds16(b + tid * 16 + p * 8192, (char*)Bs[buf] + tid * 16 + p * 8192);
  };
  auto WRITE_A = [&](int buf) {
    float v0 = ar0.x, v1 = ar0.y, v2 = ar0.z, v3 = ar0.w;
    float v4 = ar1.x, v5 = ar1.y, v6 = ar1.z, v7 = ar1.w;
    if (do_tanh) {
      v0 = fast_tanh(v0); v1 = fast_tanh(v1); v2 = fast_tanh(v2); v3 = fast_tanh(v3);
      v4 = fast_tanh(v4); v5 = fast_tanh(v5); v6 = fast_tanh(v6); v7 = fast_tanh(v7);
    }
    f16x8 h;
    h[0] = (_Float16)v0; h[1] = (_Float16)v1; h[2] = (_Float16)v2; h[3] = (_Float16)v3;
    h[4] = (_Float16)v4; h[5] = (_Float16)v5; h[6] = (_Float16)v6; h[7] = (_Float16)v7;
    *(f16x8*)((char*)As[buf] + awbyte) = h;
  };
  auto COMPUTE = [&](int buf) {
    f16x8 aF[8], bF[4];
#pragma unroll
    for (int i = 0; i < 8; ++i) {
      const int row = i * 16 + tx;
      aF[i] = *(const f16x8*)((const char*)As[buf] + row * 64 + ((qd * 16) ^ ((row & 3) << 4)));
    }
#pragma unroll
    for (int j = 0; j < 4; ++j) {
      const int n = wid * 64 + j * 16 + tx;
      bF[j] = *(const f16x8*)((const char*)Bs[buf] + n * 64 + ((qd * 16) ^ ((n & 3) << 4)));
    }
    __builtin_amdgcn_s_setprio(1);
#pragma unroll
    for (int i = 0; i < 8; ++i)
#pragma unroll
      for (int j = 0; j < 4; ++j)
        acc[i][j] = __builtin_amdgcn_mfma_f32_16x16x32_f16(aF[i], bF[j], acc[i][j], 0, 0, 0);
    __builtin_amdgcn_s_setprio(0);
  };

  // prologue
  LOAD_A(0);
  STAGE_B(0, 0);
  WRITE_A(0);      // compiler waits the float4 loads
  __syncthreads(); // drains B(0) DMA + A ds_writes

  for (int t = 0; t < 16; ++t) {
    const int cur = t & 1;
    if (t < 15) {
      LOAD_A(t + 1);          // HBM loads fly under MFMA
      STAGE_B(cur ^ 1, t + 1);
    }
    COMPUTE(cur);
    if (t < 15) WRITE_A(cur ^ 1);  // As[cur^1] last read at t-1 (barrier-protected)
    __syncthreads();               // drains B(t+1) + A writes; MFMA covered latency
  }

  // epilogue: per-wave v-dot over its 64 n, cross-wave LDS reduce, direct store
  float vv[4], bb[4];
#pragma unroll
  for (int j = 0; j < 4; ++j) {
    const int n = wid * 64 + j * 16 + tx;
    vv[j] = vvec[n];
    bb[j] = bias[n];
  }
  float* red = (float*)As;  // 8 waves x 128 rows x f32 = 4 KB, safe after barrier
#pragma unroll
  for (int i = 0; i < 8; ++i) {
#pragma unroll
    for (int r = 0; r < 4; ++r) {
      float s = 0.0f;
#pragma unroll
      for (int j = 0; j < 4; ++j)
        s = fmaf(vv[j], fast_tanh(acc[i][j][r] + bb[j]), s);
      s += __shfl_xor(s, 1);
      s += __shfl_xor(s, 2);
      s += __shfl_xor(s, 4);
      s += __shfl_xor(s, 8);
      if (tx == 0) red[wid * 128 + i * 16 + qd * 4 + r] = s;
    }
  }
  __syncthreads();
  if (tid < 128) {
    float tot = 0.0f;
#pragma unroll
    for (int w = 0; w < 8; ++w) tot += red[w * 128 + tid];
    logits[m0 + tid] = tot;
  }
}

// ---------------------------------------------------------------------------
// small/streaming kernels
// ---------------------------------------------------------------------------

__global__ void zero_kernel(float* __restrict__ p, int n) {
  const int i = blockIdx.x * 256 + threadIdx.x;
  if (i < n) p[i] = 0.0f;
}

__global__ void seg_bounds_kernel(const int* __restrict__ seg, int N,
                                  int* __restrict__ seg_start) {
  const int b = threadIdx.x;
  if (b > BATCH) return;
  int lo = 0, hi = N;
  while (lo < hi) {
    const int mid = (lo + hi) >> 1;
    if (seg[mid] < b) lo = mid + 1; else hi = mid;
  }
  seg_start[b] = lo;
}

// grid (128, 4): y=0 token (S=512), y=1 desc-anchor, y=2 desc-neg, y=3 node-seg
__global__ __launch_bounds__(256) void softmax_all_kernel(
    float* __restrict__ ltok, float* __restrict__ ldesc,
    float* __restrict__ lnode, const int* __restrict__ tlen,
    const int* __restrict__ dalen, const int* __restrict__ dnlen,
    const int* __restrict__ seg_start) {
  __shared__ float smax[4], ssum[4];
  const int b = blockIdx.x, mode = blockIdx.y, tid = threadIdx.x;
  float* l;
  int s0, s1, fill_end;
  if (mode == 0)      { l = ltok + (size_t)b * 512;          s0 = 0; s1 = tlen[b];  fill_end = 512; }
  else if (mode == 1) { l = ldesc + (size_t)b * 128;         s0 = 0; s1 = dalen[b]; fill_end = 128; }
  else if (mode == 2) { l = ldesc + 16384 + (size_t)b * 128; s0 = 0; s1 = dnlen[b]; fill_end = 128; }
  else                { l = lnode; s0 = seg_start[b]; s1 = seg_start[b + 1]; fill_end = -1; }

  float mymax = -1e30f;
  for (int s = s0 + tid; s < s1; s += 256) mymax = fmaxf(mymax, l[s]);
#pragma unroll
  for (int off = 32; off; off >>= 1) mymax = fmaxf(mymax, __shfl_xor(mymax, off));
  if ((tid & 63) == 0) smax[tid >> 6] = mymax;
  __syncthreads();
  const float bmax = fmaxf(fmaxf(smax[0], smax[1]), fmaxf(smax[2], smax[3]));
  float mysum = 0.0f;
  for (int s = s0 + tid; s < s1; s += 256) mysum += __expf(l[s] - bmax);
#pragma unroll
  for (int off = 32; off; off >>= 1) mysum += __shfl_xor(mysum, off);
  if ((tid & 63) == 0) ssum[tid >> 6] = mysum;
  __syncthreads();
  const float inv = 1.0f / (ssum[0] + ssum[1] + ssum[2] + ssum[3]);
  for (int s = s0 + tid; s < s1; s += 256) l[s] = __expf(l[s] - bmax) * inv;
  if (fill_end > 0)
    for (int s = s1 + tid; s < fill_end; s += 256) l[s] = 0.0f;
}

// grid (128, 12): c<8 token chunks, {8,9} desc-anchor, {10,11} desc-neg. fp32 src.
__global__ __launch_bounds__(256) void pool_masked_all_kernel(
    const float* __restrict__ tok_feat, const float* __restrict__ da_feat,
    const float* __restrict__ dn_feat, const float* __restrict__ ltok,
    const float* __restrict__ ldesc, float* __restrict__ tok_pool,
    float* __restrict__ da_pool, float* __restrict__ dn_pool) {
  const int b = blockIdx.x, c = blockIdx.y, tid = threadIdx.x;
  const float* feat;
  const float* w;
  float* out;
  int S, s0;
  if (c < 8)       { feat = tok_feat; S = 512; w = ltok + (size_t)b * 512;          out = tok_pool; s0 = c * 64; }
  else if (c < 10) { feat = da_feat;  S = 128; w = ldesc + (size_t)b * 128;         out = da_pool;  s0 = (c - 8) * 64; }
  else             { feat = dn_feat;  S = 128; w = ldesc + 16384 + (size_t)b * 128; out = dn_pool;  s0 = (c - 10) * 64; }
  const int h = tid * 2;
  const float* fb = feat + (size_t)b * S * HDIM + h;
  float ax = 0.0f, ay = 0.0f;
  for (int s = s0; s < s0 + 64; ++s) {
    const float wsc = w[s];
    if (wsc != 0.0f) {
      const float2 f = *(const float2*)(fb + (size_t)s * HDIM);
      ax = fmaf(wsc, f.x, ax);
      ay = fmaf(wsc, f.y, ay);
    }
  }
  atomicAdd(&out[b * HDIM + h], ax);
  atomicAdd(&out[b * HDIM + h + 1], ay);
}

// ast_pool[b,h] += sum_{n in seg b} w[n] * tanh(node_h[n,h]); grid (128, 4)
__global__ __launch_bounds__(256) void pool_seg_kernel(
    const float* __restrict__ node_h, const float* __restrict__ w,
    const int* __restrict__ seg_start, float* __restrict__ pool) {
  const int b = blockIdx.x, c = blockIdx.y, tid = threadIdx.x;
  const int h = tid * 2;
  const int s0 = seg_start[b], s1 = seg_start[b + 1];
  const int nseg = s1 - s0;
  const int chunk = (nseg + (int)gridDim.y - 1) / (int)gridDim.y;
  const int a0 = s0 + c * chunk;
  const int a1 = min(s1, a0 + chunk);
  float ax = 0.0f, ay = 0.0f;
  for (int s = a0; s < a1; ++s) {
    const float wsc = w[s];
    const float2 f = *(const float2*)(node_h + (size_t)s * HDIM + h);
    ax = fmaf(wsc, fast_tanh(f.x), ax);
    ay = fmaf(wsc, fast_tanh(f.y), ay);
  }
  atomicAdd(&pool[b * HDIM + h], ax);
  atomicAdd(&pool[b * HDIM + h + 1], ay);
}

// code-pre GEMM: parts[kb][b][n-chunk] = tanh(cat)[b][k-chunk] @ Wf[k-chunk][n-chunk]
__global__ __launch_bounds__(256) void code_gemm_kernel(
    const float* __restrict__ tok_pool, const float* __restrict__ ast_pool,
    const float* __restrict__ Wf, float* __restrict__ parts) {
  __shared__ float catS[128][65];
  __shared__ float4 wfS[64][32];
  const int nb = blockIdx.x, kb = blockIdx.y, tid = threadIdx.x;
  const int k0 = kb * 64;
  const float* src = (k0 < 512) ? (tok_pool + k0) : (ast_pool + (k0 - 512));
  for (int i = tid; i < 128 * 16; i += 256) {
    const int r = i >> 4, c4 = i & 15;
    const float4 v = *(const float4*)(src + (size_t)r * HDIM + c4 * 4);
    catS[r][c4 * 4 + 0] = fast_tanh(v.x);
    catS[r][c4 * 4 + 1] = fast_tanh(v.y);
    catS[r][c4 * 4 + 2] = fast_tanh(v.z);
    catS[r][c4 * 4 + 3] = fast_tanh(v.w);
  }
  for (int i = tid; i < 64 * 32; i += 256) {
    const int r = i >> 5, c = i & 31;
    wfS[r][c] = *(const float4*)(Wf + (size_t)(k0 + r) * HDIM + nb * 128 + c * 4);
  }
  __syncthreads();
  const int tb = tid >> 4, tn = tid & 15;
  const int b0 = tb * 8, n0l = tn * 8;
  float acc[8][8];
#pragma unroll
  for (int i = 0; i < 8; ++i)
#pragma unroll
    for (int j = 0; j < 8; ++j) acc[i][j] = 0.0f;
  for (int k = 0; k < 64; ++k) {
    float a[8];
#pragma unroll
    for (int i = 0; i < 8; ++i) a[i] = catS[b0 + i][k];
    const float4 w0 = wfS[k][tn * 2], w1 = wfS[k][tn * 2 + 1];
    const float wv[8] = {w0.x, w0.y, w0.z, w0.w, w1.x, w1.y, w1.z, w1.w};
#pragma unroll
    for (int i = 0; i < 8; ++i)
#pragma unroll
      for (int j = 0; j < 8; ++j) acc[i][j] = fmaf(a[i], wv[j], acc[i][j]);
  }
  float* dst = parts + ((size_t)kb * 128) * HDIM + nb * 128;
#pragma unroll
  for (int i = 0; i < 8; ++i) {
    const float4 o0 = {acc[i][0], acc[i][1], acc[i][2], acc[i][3]};
    const float4 o1 = {acc[i][4], acc[i][5], acc[i][6], acc[i][7]};
    *(float4*)(dst + (size_t)(b0 + i) * HDIM + n0l) = o0;
    *(float4*)(dst + (size_t)(b0 + i) * HDIM + n0l + 4) = o1;
  }
}

// per-sample hinge terms; folds code = tanh(sum_kb parts + bf). grid 128.
__global__ __launch_bounds__(256) void sims_kernel(
    const float* __restrict__ parts, const float* __restrict__ bfv,
    const float* __restrict__ da_pool, const float* __restrict__ dn_pool,
    float* __restrict__ terms) {
  __shared__ float sr[4][5];
  const int b = blockIdx.x, tid = threadIdx.x;
  float c2 = 0, a2 = 0, n2 = 0, ca = 0, cn = 0;
  for (int i = tid; i < HDIM; i += 256) {
    float pre = bfv[i];
#pragma unroll
    for (int kb = 0; kb < 16; ++kb)
      pre += parts[((size_t)kb * 128 + b) * HDIM + i];
    const float cf = fast_tanh(pre);
    const float av = fast_tanh(fast_tanh(da_pool[(size_t)b * HDIM + i]));
    const float nv = fast_tanh(fast_tanh(dn_pool[(size_t)b * HDIM + i]));
    c2 = fmaf(cf, cf, c2); a2 = fmaf(av, av, a2); n2 = fmaf(nv, nv, n2);
    ca = fmaf(cf, av, ca); cn = fmaf(cf, nv, cn);
  }
#pragma unroll
  for (int off = 32; off; off >>= 1) {
    c2 += __shfl_xor(c2, off); a2 += __shfl_xor(a2, off); n2 += __shfl_xor(n2, off);
    ca += __shfl_xor(ca, off); cn += __shfl_xor(cn, off);
  }
  const int wv = tid >> 6;
  if ((tid & 63) == 0) {
    sr[wv][0] = c2; sr[wv][1] = a2; sr[wv][2] = n2; sr[wv][3] = ca; sr[wv][4] = cn;
  }
  __syncthreads();
  if (tid == 0) {
    c2 = sr[0][0] + sr[1][0] + sr[2][0] + sr[3][0];
    a2 = sr[0][1] + sr[1][1] + sr[2][1] + sr[3][1];
    n2 = sr[0][2] + sr[1][2] + sr[2][2] + sr[3][2];
    ca = sr[0][3] + sr[1][3] + sr[2][3] + sr[3][3];
    cn = sr[0][4] + sr[1][4] + sr[2][4] + sr[3][4];
    const float nc = fmaxf(sqrtf(c2), 1e-8f);
    const float na = fmaxf(sqrtf(a2), 1e-8f);
    const float nn = fmaxf(sqrtf(n2), 1e-8f);
    terms[b] = fmaxf(0.05f - ca / (nc * na) + cn / (nc * nn), 1e-6f);
  }
}

__global__ void loss_kernel(const float* __restrict__ terms, float* __restrict__ out) {
  const int tid = threadIdx.x;  // 128
  float v = terms[tid];
#pragma unroll
  for (int off = 32; off; off >>= 1) v += __shfl_xor(v, off);
  __shared__ float sr[2];
  if ((tid & 63) == 0) sr[tid >> 6] = v;
  __syncthreads();
  if (tid == 0) out[0] = (sr[0] + sr[1]) * (1.0f / (float)BATCH);
}

// ===========================================================================

extern "C" void kernel_launch(void* const* d_in, const int* in_sizes, int n_in,
                              void* d_out, int out_size, void* d_ws, size_t ws_size,
                              hipStream_t stream) {
  (void)in_sizes; (void)n_in; (void)out_size; (void)ws_size;
  const float* token_feat = (const float*)d_in[0];
  const int*   token_len  = (const int*)d_in[1];
  const float* node_h     = (const float*)d_in[2];
  const int*   seg_ids    = (const int*)d_in[3];
  const float* da_feat    = (const float*)d_in[4];
  const int*   da_len     = (const int*)d_in[5];
  const float* dn_feat    = (const float*)d_in[6];
  const int*   dn_len     = (const int*)d_in[7];
  const float* Wt = (const float*)d_in[8];
  const float* bt = (const float*)d_in[9];
  const float* vt = (const float*)d_in[10];
  const float* Wa = (const float*)d_in[12];
  const float* ba = (const float*)d_in[13];
  const float* va = (const float*)d_in[14];
  const float* Wd = (const float*)d_in[16];
  const float* bd = (const float*)d_in[17];
  const float* vd = (const float*)d_in[18];
  const float* Wf  = (const float*)d_in[20];
  const float* bfv = (const float*)d_in[21];

  const int MTOK = 65536;
  const int MDESC2 = 32768;
  const int NNODES = 65536;

  float* ws = (float*)d_ws;
  float* logits_tok  = ws;                       // 65536 (direct-stored)
  float* logits_node = logits_tok + MTOK;        // 65536
  float* logits_desc = logits_node + NNODES;     // 32768 (da ++ dn)
  float* tok_pool    = logits_desc + MDESC2;     // 4 pools, atomic -> pre-zeroed
  float* ast_pool    = tok_pool + 128 * HDIM;
  float* da_pool     = ast_pool + 128 * HDIM;
  float* dn_pool     = da_pool + 128 * HDIM;
  float* terms       = dn_pool + 128 * HDIM;     // 128
  int*   seg_start   = (int*)(terms + 128);      // 256 slot
  float* parts       = (float*)(seg_start + 256);  // 16*128*512
  _Float16* W2t = (_Float16*)(parts + 16 * 128 * HDIM);
  _Float16* W2a = W2t + HDIM * HDIM;
  _Float16* W2d = W2a + HDIM * HDIM;

  // zero only the atomically-accumulated pools (1 MB)
  zero_kernel<<<dim3((4 * 128 * HDIM + 255) / 256), 256, 0, stream>>>(tok_pool, 4 * 128 * HDIM);
  seg_bounds_kernel<<<1, 256, 0, stream>>>(seg_ids, NNODES, seg_start);
  cvt_w3_kernel<<<dim3(128, 3), 256, 0, stream>>>(Wt, Wa, Wd, W2t, W2a, W2d);

  // one merged GEMM launch: 512 tok + 512 node + 128 da + 128 dn = 1280 blocks
  gemm_logits_merged_kernel<<<1280, 512, 0, stream>>>(
      token_feat, node_h, da_feat, dn_feat, W2t, W2a, W2d,
      bt, vt, ba, va, bd, vd, logits_tok, logits_node, logits_desc);

  softmax_all_kernel<<<dim3(BATCH, 4), 256, 0, stream>>>(
      logits_tok, logits_desc, logits_node, token_len, da_len, dn_len, seg_start);

  pool_masked_all_kernel<<<dim3(BATCH, 12), 256, 0, stream>>>(
      token_feat, da_feat, dn_feat, logits_tok, logits_desc,
      tok_pool, da_pool, dn_pool);
  pool_seg_kernel<<<dim3(BATCH, 4), 256, 0, stream>>>(
      node_h, logits_node, seg_start, ast_pool);

  code_gemm_kernel<<<dim3(4, 16), 256, 0, stream>>>(tok_pool, ast_pool, Wf, parts);
  sims_kernel<<<BATCH, 256, 0, stream>>>(parts, bfv, da_pool, dn_pool, terms);
  loss_kernel<<<1, 128, 0, stream>>>(terms, (float*)d_out);
}